// Round 9
// baseline (208.558 us; speedup 1.0000x reference)
//
#include <hip/hip_runtime.h>
#include <math.h>

#define DIM 768
#define HEADS 16
#define DKH 48          // head dim
#define SEQ 2048
#define BATCH 2
#define M_TOT (BATCH*SEQ)                  // 4096
#define PART  (32*2048*48)                 // elems per split-K O partial
#define QTOT  (32*2048)                    // total (bh, s) rows

typedef __bf16 v8bf16 __attribute__((ext_vector_type(8)));
typedef __bf16 v4bf16 __attribute__((ext_vector_type(4)));
typedef float  v4f32  __attribute__((ext_vector_type(4)));

#define GLDS(g, l) __builtin_amdgcn_global_load_lds( \
    (const __attribute__((address_space(1))) void*)(g), \
    (__attribute__((address_space(3))) void*)(l), 16, 0, 0)

// ---------------------------------------------------------------------------
// fp32 -> bf16 conversion of x and the 4 weight matrices.
// ---------------------------------------------------------------------------
#define XN4 786432      // 4096*768/4
#define WN4 147456      // 768*768/4
__global__ __launch_bounds__(256) void convert_kernel(
    const float* __restrict__ x,
    const float* __restrict__ Wq, const float* __restrict__ Wk,
    const float* __restrict__ Wv, const float* __restrict__ Wo,
    __bf16* __restrict__ xb,
    __bf16* __restrict__ Wqb, __bf16* __restrict__ Wkb,
    __bf16* __restrict__ Wvb, __bf16* __restrict__ Wob)
{
    int f = blockIdx.x * 256 + threadIdx.x;
    const float* src; __bf16* dst;
    if (f < XN4)                { src = x;  dst = xb; }
    else if (f < XN4 + WN4)     { src = Wq; dst = Wqb; f -= XN4; }
    else if (f < XN4 + 2*WN4)   { src = Wk; dst = Wkb; f -= XN4 + WN4; }
    else if (f < XN4 + 3*WN4)   { src = Wv; dst = Wvb; f -= XN4 + 2*WN4; }
    else                        { src = Wo; dst = Wob; f -= XN4 + 3*WN4; }
    float4 v = ((const float4*)src)[f];
    v4bf16 b;
    b[0] = (__bf16)v.x; b[1] = (__bf16)v.y;
    b[2] = (__bf16)v.z; b[3] = (__bf16)v.w;
    *(v4bf16*)&dst[(size_t)f * 4] = b;
}

// ---------------------------------------------------------------------------
// QKV MFMA GEMM: C = A @ W^T, A[4096][768] bf16, W[768][768] bf16.
// 128x96 tile -> grid (8,32,3) = 768 blocks = 3.00 blocks/CU (no tail).
// z=0: Q (scaled by log2e/sqrt(48)) -> [B,H,S,dk]. z=1: K -> [B,H,S,dk].
// z=2: V -> TRANSPOSED [B,H,dk,S] via b64 stores.
// ---------------------------------------------------------------------------
__global__ __launch_bounds__(256) void qkv_mfma_kernel(
    const __bf16* __restrict__ xb,
    const __bf16* __restrict__ Wqb, const float* __restrict__ bq,
    const __bf16* __restrict__ Wkb, const float* __restrict__ bk,
    const __bf16* __restrict__ Wvb, const float* __restrict__ bv,
    __bf16* __restrict__ Qo, __bf16* __restrict__ Ko, __bf16* __restrict__ Vo)
{
    __shared__ __bf16 As[128 * 32];
    __shared__ __bf16 Bs[128 * 32];

    const int z = blockIdx.z;
    const __bf16* W   = (z == 0) ? Wqb : ((z == 1) ? Wkb : Wvb);
    const float* bias = (z == 0) ? bq  : ((z == 1) ? bk  : bv);
    __bf16* out       = (z == 0) ? Qo  : ((z == 1) ? Ko  : Vo);

    const int m0 = blockIdx.y * 128;
    const int n0 = blockIdx.x * 96;
    const int t  = threadIdx.x;
    const int w    = t >> 6;
    const int lane = t & 63;
    const int low4 = lane & 15;
    const int quad = lane >> 4;
    const int wm = w >> 1, wn = w & 1;

    const int lrow = w * 32 + (lane >> 2);   // LDS row this lane stages
    const int lcol = (lane & 3) * 8;         // k-element offset (16 B)

    v4f32 acc[4][3];
#pragma unroll
    for (int i = 0; i < 4; ++i)
#pragma unroll
        for (int j = 0; j < 3; ++j)
            acc[i][j] = (v4f32){0.f, 0.f, 0.f, 0.f};

    for (int k0 = 0; k0 < DIM; k0 += 32) {
        GLDS(xb + (size_t)(m0 + lrow)      * DIM + k0 + lcol, &As[lrow * 32 + lcol]);
        GLDS(xb + (size_t)(m0 + lrow + 16) * DIM + k0 + lcol, &As[(lrow + 16) * 32 + lcol]);
        GLDS(W  + (size_t)(n0 + lrow)      * DIM + k0 + lcol, &Bs[lrow * 32 + lcol]);
        GLDS(W  + (size_t)(n0 + lrow + 16) * DIM + k0 + lcol, &Bs[(lrow + 16) * 32 + lcol]);
        __syncthreads();

        v8bf16 af[4], bf[3];
#pragma unroll
        for (int i = 0; i < 4; ++i)
            af[i] = *(const v8bf16*)&As[(wm * 64 + i * 16 + low4) * 32 + quad * 8];
#pragma unroll
        for (int j = 0; j < 3; ++j)
            bf[j] = *(const v8bf16*)&Bs[(wn * 48 + j * 16 + low4) * 32 + quad * 8];
#pragma unroll
        for (int i = 0; i < 4; ++i)
#pragma unroll
            for (int j = 0; j < 3; ++j)
                acc[i][j] = __builtin_amdgcn_mfma_f32_16x16x32_bf16(af[i], bf[j], acc[i][j], 0, 0, 0);
        __syncthreads();
    }

    // scale = log2(e)/sqrt(48), folded into Q so attention can use exp2
    const float scale = 0.2082351055f;
#pragma unroll
    for (int j = 0; j < 3; ++j) {
        const int e = n0 + wn * 48 + j * 16 + low4;
        const float b = bias[e];
        const int h = e / DKH;
        const int d = e - h * DKH;
        if (z == 2) {
            // V^T: 4 consecutive s per lane -> one b64 store
#pragma unroll
            for (int i = 0; i < 4; ++i) {
                const int m_base = m0 + wm * 64 + i * 16 + quad * 4;
                const int bb = m_base >> 11;
                const int s  = m_base & (SEQ - 1);
                v4bf16 pk;
#pragma unroll
                for (int r = 0; r < 4; ++r) pk[r] = (__bf16)(acc[i][j][r] + b);
                *(v4bf16*)&out[((size_t)(bb * HEADS + h) * DKH + d) * SEQ + s] = pk;
            }
        } else {
#pragma unroll
            for (int i = 0; i < 4; ++i) {
#pragma unroll
                for (int r = 0; r < 4; ++r) {
                    const int m  = m0 + wm * 64 + i * 16 + quad * 4 + r;
                    const int bb = m >> 11;
                    const int s  = m & (SEQ - 1);
                    float v = acc[i][j][r] + b;
                    if (z == 0) v *= scale;
                    out[((size_t)(bb * HEADS + h) * SEQ + s) * DKH + d] = (__bf16)v;
                }
            }
        }
    }
}

// ---------------------------------------------------------------------------
// Output projection: out[m][e] = ctx[m][:] . Wo[e][:] + bo[e], fp32 out.
// 64x96 tile -> grid (8,64) = 512 blocks = 2.00 blocks/CU.
// ---------------------------------------------------------------------------
__global__ __launch_bounds__(256) void out_mfma_kernel(
    const __bf16* __restrict__ ctx, const __bf16* __restrict__ Wob,
    const float* __restrict__ bo, float* __restrict__ outp)
{
    __shared__ __bf16 As[64 * 32];
    __shared__ __bf16 Bs[128 * 32];

    const int m0 = blockIdx.y * 64;
    const int n0 = blockIdx.x * 96;
    const int t  = threadIdx.x;
    const int w    = t >> 6;
    const int lane = t & 63;
    const int low4 = lane & 15;
    const int quad = lane >> 4;
    const int wm = w >> 1, wn = w & 1;

    const int arow = w * 16 + (lane >> 2);   // As staging row (0..63)
    const int brow = w * 32 + (lane >> 2);   // Bs staging rows (0..127)
    const int lcol = (lane & 3) * 8;

    v4f32 acc[2][3];
#pragma unroll
    for (int i = 0; i < 2; ++i)
#pragma unroll
        for (int j = 0; j < 3; ++j)
            acc[i][j] = (v4f32){0.f, 0.f, 0.f, 0.f};

    for (int k0 = 0; k0 < DIM; k0 += 32) {
        GLDS(ctx + (size_t)(m0 + arow)      * DIM + k0 + lcol, &As[arow * 32 + lcol]);
        GLDS(Wob + (size_t)(n0 + brow)      * DIM + k0 + lcol, &Bs[brow * 32 + lcol]);
        GLDS(Wob + (size_t)(n0 + brow + 16) * DIM + k0 + lcol, &Bs[(brow + 16) * 32 + lcol]);
        __syncthreads();

        v8bf16 af[2], bf[3];
#pragma unroll
        for (int i = 0; i < 2; ++i)
            af[i] = *(const v8bf16*)&As[(wm * 32 + i * 16 + low4) * 32 + quad * 8];
#pragma unroll
        for (int j = 0; j < 3; ++j)
            bf[j] = *(const v8bf16*)&Bs[(wn * 48 + j * 16 + low4) * 32 + quad * 8];
#pragma unroll
        for (int i = 0; i < 2; ++i)
#pragma unroll
            for (int j = 0; j < 3; ++j)
                acc[i][j] = __builtin_amdgcn_mfma_f32_16x16x32_bf16(af[i], bf[j], acc[i][j], 0, 0, 0);
        __syncthreads();
    }

#pragma unroll
    for (int j = 0; j < 3; ++j) {
        const int e = n0 + wn * 48 + j * 16 + low4;
        const float b = bo[e];
#pragma unroll
        for (int i = 0; i < 2; ++i) {
#pragma unroll
            for (int r = 0; r < 4; ++r) {
                const int m = m0 + wm * 32 + i * 16 + quad * 4 + r;
                outp[(size_t)m * DIM + e] = acc[i][j][r] + b;
            }
        }
    }
}

// ---------------------------------------------------------------------------
// BARRIER-FREE MFMA flash attention, SPLIT-K (z = key half), no-max softmax
// (exact: shift-invariant + bounded scores; Q pre-scaled by log2e/sqrt(48)).
// All Q/K/V MFMA fragments are read DIRECTLY from global (L1/L2-hot tiles):
//  - Q/K A/B-frags: contiguous 16B chunks of [s][48] rows; the dk=48..63
//    upper half is a zero fragment (predicated on quad<2) - no padding.
//  - V^T B-frags: contiguous 16B chunks of the [d][S] layout.
// Only Ps lives in LDS (wave-private rows, XOR-swizzled) -> the k-loop has
// ZERO __syncthreads: waves free-run, exp2 VALU overlaps other waves' MFMA.
// Outputs UNNORMALIZED O (bf16) + l (fp32); merge kernel divides.
// ---------------------------------------------------------------------------
__global__ __launch_bounds__(256) void attention_kernel(
    const __bf16* __restrict__ Q, const __bf16* __restrict__ K,
    const __bf16* __restrict__ Vt_g, __bf16* __restrict__ Opart,
    float* __restrict__ lbuf)
{
    __shared__ __bf16 Ps[128][72];  // [query][key], XOR-swizzled columns

    const int bh   = blockIdx.y;
    const int q0   = blockIdx.x * 128;
    const int kh0  = blockIdx.z * 1024;   // key half start
    const int t    = threadIdx.x;
    const int w    = t >> 6;
    const int lane = t & 63;
    const int low4 = lane & 15;
    const int quad = lane >> 4;

    const __bf16* Qbh = Q    + (size_t)bh * SEQ * DKH;
    const __bf16* Kbh = K    + (size_t)bh * SEQ * DKH;
    const __bf16* Vbh = Vt_g + (size_t)bh * SEQ * DKH;  // [d][s]

    v8bf16 zz8;
#pragma unroll
    for (int jj = 0; jj < 8; ++jj) zz8[jj] = (__bf16)0.f;

    // ---- Q A-fragments straight from global ----
    v8bf16 aq[2][2];
#pragma unroll
    for (int i = 0; i < 2; ++i) {
        const __bf16* qrow = &Qbh[(size_t)(q0 + w * 32 + i * 16 + low4) * DKH];
        aq[i][0] = *(const v8bf16*)&qrow[quad * 8];
        aq[i][1] = zz8;
        if (quad < 2)
            aq[i][1] = *(const v8bf16*)&qrow[32 + quad * 8];
    }

    // ones B-fragment for l row-sums
    v8bf16 ones;
#pragma unroll
    for (int jj = 0; jj < 8; ++jj) ones[jj] = (__bf16)1.0f;

    v4f32 lacc[2];
    v4f32 oacc[2][3];
#pragma unroll
    for (int i = 0; i < 2; ++i) {
        lacc[i] = (v4f32){0.f, 0.f, 0.f, 0.f};
#pragma unroll
        for (int dt = 0; dt < 3; ++dt)
            oacc[i][dt] = (v4f32){0.f, 0.f, 0.f, 0.f};
    }

    const int pswz = (low4 >> 2) * 8;   // Ps read swizzle

    for (int k0 = kh0; k0 < kh0 + 1024; k0 += 64) {
        // ---- K B-fragments straight from global ----
        v8bf16 bk0[4], bk1[4];
#pragma unroll
        for (int tn = 0; tn < 4; ++tn) {
            const __bf16* krow = &Kbh[(size_t)(k0 + tn * 16 + low4) * DKH];
            bk0[tn] = *(const v8bf16*)&krow[quad * 8];
            bk1[tn] = zz8;
            if (quad < 2)
                bk1[tn] = *(const v8bf16*)&krow[32 + quad * 8];
        }
        // ---- V^T B-fragments straight from global ----
        v8bf16 bv0[3], bv1[3];
#pragma unroll
        for (int dt = 0; dt < 3; ++dt) {
            const __bf16* vrow = &Vbh[(size_t)(dt * 16 + low4) * SEQ + k0];
            bv0[dt] = *(const v8bf16*)&vrow[quad * 8];
            bv1[dt] = *(const v8bf16*)&vrow[32 + quad * 8];
        }

        // ---- per query tile: S = Q K^T, exp2, P->LDS, O += P V, l += P 1 ----
#pragma unroll
        for (int i = 0; i < 2; ++i) {
            v4f32 sacc[4];
#pragma unroll
            for (int tn = 0; tn < 4; ++tn) {
                v4f32 c = {0.f, 0.f, 0.f, 0.f};
                c = __builtin_amdgcn_mfma_f32_16x16x32_bf16(aq[i][0], bk0[tn], c, 0, 0, 0);
                c = __builtin_amdgcn_mfma_f32_16x16x32_bf16(aq[i][1], bk1[tn], c, 0, 0, 0);
                sacc[tn] = c;
            }
#pragma unroll
            for (int tn = 0; tn < 4; ++tn) {
#pragma unroll
                for (int r = 0; r < 4; ++r) {
                    const float p = __builtin_amdgcn_exp2f(sacc[tn][r]);
                    // writer row = w*32+i*16+quad*4+r -> (row>>2)&3 == quad
                    Ps[w * 32 + i * 16 + quad * 4 + r][(tn * 16 + low4) ^ (quad * 8)] = (__bf16)p;
                }
            }
            // wave-private rows: only wave-internal lgkmcnt needed (compiler)
            v8bf16 ap0 = *(const v8bf16*)&Ps[w * 32 + i * 16 + low4][(quad * 8) ^ pswz];
            v8bf16 ap1 = *(const v8bf16*)&Ps[w * 32 + i * 16 + low4][(32 + quad * 8) ^ pswz];
#pragma unroll
            for (int dt = 0; dt < 3; ++dt) {
                oacc[i][dt] = __builtin_amdgcn_mfma_f32_16x16x32_bf16(ap0, bv0[dt], oacc[i][dt], 0, 0, 0);
                oacc[i][dt] = __builtin_amdgcn_mfma_f32_16x16x32_bf16(ap1, bv1[dt], oacc[i][dt], 0, 0, 0);
            }
            lacc[i] = __builtin_amdgcn_mfma_f32_16x16x32_bf16(ap0, ones, lacc[i], 0, 0, 0);
            lacc[i] = __builtin_amdgcn_mfma_f32_16x16x32_bf16(ap1, ones, lacc[i], 0, 0, 0);
        }
    }

    // ---- write unnormalized O partial (bf16) + l (fp32) ----
    const int kh = blockIdx.z;
#pragma unroll
    for (int i = 0; i < 2; ++i) {
#pragma unroll
        for (int r = 0; r < 4; ++r) {
            const int s  = q0 + w * 32 + i * 16 + quad * 4 + r;
            const int qg = bh * SEQ + s;
            __bf16* dst = Opart + (size_t)kh * PART + (size_t)qg * 48;
#pragma unroll
            for (int dt = 0; dt < 3; ++dt)
                dst[dt * 16 + low4] = (__bf16)oacc[i][dt][r];
            if (low4 == 0)
                lbuf[kh * QTOT + qg] = lacc[i][r];
        }
    }
}

// ---------------------------------------------------------------------------
// Merge split-K partials: ctx = (O0 + O1) / (l0 + l1), bf16 out [B,S,768].
// ---------------------------------------------------------------------------
__global__ __launch_bounds__(256) void merge_kernel(
    const __bf16* __restrict__ Opart, const float* __restrict__ lbuf,
    __bf16* __restrict__ ctx)
{
    const int f  = (blockIdx.x * 256 + threadIdx.x) * 8;  // < 32*2048*48
    const int q  = f / 48;          // bh*2048 + s
    const int d0 = f - q * 48;
    v8bf16 a0 = *(const v8bf16*)&Opart[f];
    v8bf16 a1 = *(const v8bf16*)&Opart[PART + f];
    const float inv = 1.0f / (lbuf[q] + lbuf[QTOT + q]);
    const int bh = q >> 11, s = q & (SEQ - 1);
    const int h = bh & (HEADS - 1), bb = bh >> 4;
    __bf16* dst = ctx + ((size_t)(bb * SEQ + s) * DIM) + h * DKH + d0;
    v8bf16 o;
#pragma unroll
    for (int j = 0; j < 8; ++j)
        o[j] = (__bf16)(((float)a0[j] + (float)a1[j]) * inv);
    *(v8bf16*)dst = o;
}

// ---------------------------------------------------------------------------
extern "C" void kernel_launch(void* const* d_in, const int* in_sizes, int n_in,
                              void* d_out, int out_size, void* d_ws, size_t ws_size,
                              hipStream_t stream) {
    const float* x  = (const float*)d_in[0];
    const float* Wq = (const float*)d_in[1];
    const float* bq = (const float*)d_in[2];
    const float* Wk = (const float*)d_in[3];
    const float* bk = (const float*)d_in[4];
    const float* Wv = (const float*)d_in[5];
    const float* bv = (const float*)d_in[6];
    const float* Wo = (const float*)d_in[7];
    const float* bo = (const float*)d_in[8];
    float* out = (float*)d_out;

    char* ws = (char*)d_ws;
    const size_t XB  = (size_t)M_TOT * DIM * 2;    // 6291456
    const size_t WBP = (size_t)800 * DIM * 2;      // 1228800 (768 rows + 32 pad)
    __bf16* xb  = (__bf16*)(ws);
    __bf16* Wqb = (__bf16*)(ws + XB);
    __bf16* Wkb = (__bf16*)(ws + XB + WBP);
    __bf16* Wvb = (__bf16*)(ws + XB + 2 * WBP);
    __bf16* Wob = (__bf16*)(ws + XB + 3 * WBP);
    __bf16* Qb  = (__bf16*)(ws + XB + 4 * WBP);
    __bf16* Kb  = (__bf16*)(ws + 2 * XB + 4 * WBP);
    __bf16* Vb  = (__bf16*)(ws + 3 * XB + 4 * WBP);  // [B,H,dk,S]
    __bf16* CTX = (__bf16*)(ws + 4 * XB + 4 * WBP);
    __bf16* Opart = (__bf16*)(ws + 5 * XB + 4 * WBP);              // 2*PART bf16
    float*  lbuf  = (float*)(ws + 5 * XB + 4 * WBP + (size_t)2 * PART * 2);

    // 0) fp32 -> bf16 conversion of x and weights
    convert_kernel<<<dim3((XN4 + 4 * WN4) / 256), 256, 0, stream>>>(
        x, Wq, Wk, Wv, Wo, xb, Wqb, Wkb, Wvb, Wob);

    // 1) QKV projections (MFMA): grid (768/96=8, 4096/128=32, 3) = 768 blocks
    qkv_mfma_kernel<<<dim3(8, 32, 3), 256, 0, stream>>>(
        xb, Wqb, bq, Wkb, bk, Wvb, bv, Qb, Kb, Vb);

    // 2) attention split-K: grid (S/128=16 q-tiles, B*H=32, 2 key halves)
    attention_kernel<<<dim3(16, 32, 2), 256, 0, stream>>>(Qb, Kb, Vb, Opart, lbuf);

    // 2b) merge partials: 32*2048*48/8/256 = 1536 blocks
    merge_kernel<<<dim3(1536), 256, 0, stream>>>(Opart, lbuf, CTX);

    // 3) output projection (MFMA): grid (768/96=8, 4096/64=64) = 512 blocks
    out_mfma_kernel<<<dim3(8, 64), 256, 0, stream>>>(CTX, Wob, bo, out);
}

// Round 10
// 181.039 us; speedup vs baseline: 1.1520x; 1.1520x over previous
//
#include <hip/hip_runtime.h>
#include <math.h>

#define DIM 768
#define HEADS 16
#define DKH 48          // head dim
#define SEQ 2048
#define BATCH 2
#define M_TOT (BATCH*SEQ)                  // 4096
#define PART  (32*2048*48)                 // elems per split-K O partial
#define QTOT  (32*2048)                    // total (bh, s) rows

typedef __bf16 v8bf16 __attribute__((ext_vector_type(8)));
typedef __bf16 v4bf16 __attribute__((ext_vector_type(4)));
typedef float  v4f32  __attribute__((ext_vector_type(4)));

#define GLDS(g, l) __builtin_amdgcn_global_load_lds( \
    (const __attribute__((address_space(1))) void*)(g), \
    (__attribute__((address_space(3))) void*)(l), 16, 0, 0)

// ---------------------------------------------------------------------------
// fp32 -> bf16 conversion of x and the 4 weight matrices.
// ---------------------------------------------------------------------------
#define XN4 786432      // 4096*768/4
#define WN4 147456      // 768*768/4
__global__ __launch_bounds__(256) void convert_kernel(
    const float* __restrict__ x,
    const float* __restrict__ Wq, const float* __restrict__ Wk,
    const float* __restrict__ Wv, const float* __restrict__ Wo,
    __bf16* __restrict__ xb,
    __bf16* __restrict__ Wqb, __bf16* __restrict__ Wkb,
    __bf16* __restrict__ Wvb, __bf16* __restrict__ Wob)
{
    int f = blockIdx.x * 256 + threadIdx.x;
    const float* src; __bf16* dst;
    if (f < XN4)                { src = x;  dst = xb; }
    else if (f < XN4 + WN4)     { src = Wq; dst = Wqb; f -= XN4; }
    else if (f < XN4 + 2*WN4)   { src = Wk; dst = Wkb; f -= XN4 + WN4; }
    else if (f < XN4 + 3*WN4)   { src = Wv; dst = Wvb; f -= XN4 + 2*WN4; }
    else                        { src = Wo; dst = Wob; f -= XN4 + 3*WN4; }
    float4 v = ((const float4*)src)[f];
    v4bf16 b;
    b[0] = (__bf16)v.x; b[1] = (__bf16)v.y;
    b[2] = (__bf16)v.z; b[3] = (__bf16)v.w;
    *(v4bf16*)&dst[(size_t)f * 4] = b;
}

// ---------------------------------------------------------------------------
// QKV MFMA GEMM, BK=64 via TWO stride-32 LDS planes per operand (keeps the
// m97-proven 64B row pitch conflict behavior AND the GLDS wave-uniform-base
// constraint). 128x96 tile -> grid (8,32,3) = 768 blocks = 3/CU, 12 k-iters.
// z=0: Q (scaled by log2e/sqrt(48)) -> [B,H,S,dk]. z=1: K -> [B,H,S,dk].
// z=2: V -> TRANSPOSED [B,H,dk,S] via b64 stores.
// ---------------------------------------------------------------------------
__global__ __launch_bounds__(256) void qkv_mfma_kernel(
    const __bf16* __restrict__ xb,
    const __bf16* __restrict__ Wqb, const float* __restrict__ bq,
    const __bf16* __restrict__ Wkb, const float* __restrict__ bk,
    const __bf16* __restrict__ Wvb, const float* __restrict__ bv,
    __bf16* __restrict__ Qo, __bf16* __restrict__ Ko, __bf16* __restrict__ Vo)
{
    __shared__ __bf16 As0[128 * 32];
    __shared__ __bf16 As1[128 * 32];
    __shared__ __bf16 Bs0[128 * 32];
    __shared__ __bf16 Bs1[128 * 32];

    const int z = blockIdx.z;
    const __bf16* W   = (z == 0) ? Wqb : ((z == 1) ? Wkb : Wvb);
    const float* bias = (z == 0) ? bq  : ((z == 1) ? bk  : bv);
    __bf16* out       = (z == 0) ? Qo  : ((z == 1) ? Ko  : Vo);

    const int m0 = blockIdx.y * 128;
    const int n0 = blockIdx.x * 96;
    const int t  = threadIdx.x;
    const int w    = t >> 6;
    const int lane = t & 63;
    const int low4 = lane & 15;
    const int quad = lane >> 4;
    const int wm = w >> 1, wn = w & 1;

    const int lrow = w * 32 + (lane >> 2);   // LDS row this lane stages
    const int lcol = (lane & 3) * 8;         // k-element offset (16 B)

    v4f32 acc[4][3];
#pragma unroll
    for (int i = 0; i < 4; ++i)
#pragma unroll
        for (int j = 0; j < 3; ++j)
            acc[i][j] = (v4f32){0.f, 0.f, 0.f, 0.f};

    for (int k0 = 0; k0 < DIM; k0 += 64) {
        GLDS(xb + (size_t)(m0 + lrow)      * DIM + k0 + lcol,      &As0[lrow * 32 + lcol]);
        GLDS(xb + (size_t)(m0 + lrow + 16) * DIM + k0 + lcol,      &As0[(lrow + 16) * 32 + lcol]);
        GLDS(xb + (size_t)(m0 + lrow)      * DIM + k0 + 32 + lcol, &As1[lrow * 32 + lcol]);
        GLDS(xb + (size_t)(m0 + lrow + 16) * DIM + k0 + 32 + lcol, &As1[(lrow + 16) * 32 + lcol]);
        GLDS(W  + (size_t)(n0 + lrow)      * DIM + k0 + lcol,      &Bs0[lrow * 32 + lcol]);
        GLDS(W  + (size_t)(n0 + lrow + 16) * DIM + k0 + lcol,      &Bs0[(lrow + 16) * 32 + lcol]);
        GLDS(W  + (size_t)(n0 + lrow)      * DIM + k0 + 32 + lcol, &Bs1[lrow * 32 + lcol]);
        GLDS(W  + (size_t)(n0 + lrow + 16) * DIM + k0 + 32 + lcol, &Bs1[(lrow + 16) * 32 + lcol]);
        __syncthreads();

        v8bf16 af0[4], af1[4], bf0[3], bf1[3];
#pragma unroll
        for (int i = 0; i < 4; ++i) {
            af0[i] = *(const v8bf16*)&As0[(wm * 64 + i * 16 + low4) * 32 + quad * 8];
            af1[i] = *(const v8bf16*)&As1[(wm * 64 + i * 16 + low4) * 32 + quad * 8];
        }
#pragma unroll
        for (int j = 0; j < 3; ++j) {
            bf0[j] = *(const v8bf16*)&Bs0[(wn * 48 + j * 16 + low4) * 32 + quad * 8];
            bf1[j] = *(const v8bf16*)&Bs1[(wn * 48 + j * 16 + low4) * 32 + quad * 8];
        }
#pragma unroll
        for (int i = 0; i < 4; ++i)
#pragma unroll
            for (int j = 0; j < 3; ++j) {
                acc[i][j] = __builtin_amdgcn_mfma_f32_16x16x32_bf16(af0[i], bf0[j], acc[i][j], 0, 0, 0);
                acc[i][j] = __builtin_amdgcn_mfma_f32_16x16x32_bf16(af1[i], bf1[j], acc[i][j], 0, 0, 0);
            }
        __syncthreads();
    }

    // scale = log2(e)/sqrt(48), folded into Q so attention can use exp2
    const float scale = 0.2082351055f;
#pragma unroll
    for (int j = 0; j < 3; ++j) {
        const int e = n0 + wn * 48 + j * 16 + low4;
        const float b = bias[e];
        const int h = e / DKH;
        const int d = e - h * DKH;
        if (z == 2) {
            // V^T: 4 consecutive s per lane -> one b64 store
#pragma unroll
            for (int i = 0; i < 4; ++i) {
                const int m_base = m0 + wm * 64 + i * 16 + quad * 4;
                const int bb = m_base >> 11;
                const int s  = m_base & (SEQ - 1);
                v4bf16 pk;
#pragma unroll
                for (int r = 0; r < 4; ++r) pk[r] = (__bf16)(acc[i][j][r] + b);
                *(v4bf16*)&out[((size_t)(bb * HEADS + h) * DKH + d) * SEQ + s] = pk;
            }
        } else {
#pragma unroll
            for (int i = 0; i < 4; ++i) {
#pragma unroll
                for (int r = 0; r < 4; ++r) {
                    const int m  = m0 + wm * 64 + i * 16 + quad * 4 + r;
                    const int bb = m >> 11;
                    const int s  = m & (SEQ - 1);
                    float v = acc[i][j][r] + b;
                    if (z == 0) v *= scale;
                    out[((size_t)(bb * HEADS + h) * SEQ + s) * DKH + d] = (__bf16)v;
                }
            }
        }
    }
}

// ---------------------------------------------------------------------------
// lsum: invl[qg] = 1 / (l0[qg] + l1[qg]).  65536 values.
// ---------------------------------------------------------------------------
__global__ __launch_bounds__(256) void lsum_kernel(
    const float* __restrict__ lbuf, float* __restrict__ invl)
{
    const int q = blockIdx.x * 256 + threadIdx.x;
    invl[q] = 1.0f / (lbuf[q] + lbuf[QTOT + q]);
}

// ---------------------------------------------------------------------------
// Output projection with FUSED split-K merge:
// out[m][e] = sum_k ctx[m][k] Wo[e][k] + bo[e],
// ctx[m][h*48+d] = (O0[qg][d] + O1[qg][d]) * invl[qg] formed during A-staging
// (8-elem chunks never cross a head boundary: 48 % 8 == 0).
// 64x96 tile -> grid (8,64) = 512 blocks = 2.00 blocks/CU.
// ---------------------------------------------------------------------------
__global__ __launch_bounds__(256) void out_mfma_kernel(
    const __bf16* __restrict__ Opart, const float* __restrict__ invl,
    const __bf16* __restrict__ Wob, const float* __restrict__ bo,
    float* __restrict__ outp)
{
    __shared__ __bf16 As[64 * 32];
    __shared__ __bf16 Bs[128 * 32];

    const int m0 = blockIdx.y * 64;
    const int n0 = blockIdx.x * 96;
    const int t  = threadIdx.x;
    const int w    = t >> 6;
    const int lane = t & 63;
    const int low4 = lane & 15;
    const int quad = lane >> 4;
    const int wm = w >> 1, wn = w & 1;

    const int arow = w * 16 + (lane >> 2);   // A row this thread stages (0..63)
    const int ac8  = (lane & 3) * 8;         // col chunk within BK=32
    const int brow = w * 32 + (lane >> 2);   // Bs staging rows (0..127)
    const int lcol = (lane & 3) * 8;

    // fixed per-thread row coords for the merge
    const int m_st = m0 + arow;
    const int bb_st = m_st >> 11;
    const int s_st  = m_st & (SEQ - 1);

    v4f32 acc[2][3];
#pragma unroll
    for (int i = 0; i < 2; ++i)
#pragma unroll
        for (int j = 0; j < 3; ++j)
            acc[i][j] = (v4f32){0.f, 0.f, 0.f, 0.f};

    for (int k0 = 0; k0 < DIM; k0 += 32) {
        // ---- fused merge A-staging ----
        {
            const int e8 = k0 + ac8;             // 8-elem chunk start
            const int h  = e8 / DKH;
            const int d0 = e8 - h * DKH;
            const int qg = (bb_st * HEADS + h) * SEQ + s_st;
            const __bf16* p0 = &Opart[(size_t)qg * 48 + d0];
            v8bf16 a0 = *(const v8bf16*)p0;
            v8bf16 a1 = *(const v8bf16*)&p0[PART];
            const float inv = invl[qg];
            v8bf16 packed;
#pragma unroll
            for (int jj = 0; jj < 8; ++jj)
                packed[jj] = (__bf16)(((float)a0[jj] + (float)a1[jj]) * inv);
            *(v8bf16*)&As[arow * 32 + ac8] = packed;
        }
        GLDS(Wob + (size_t)(n0 + brow)      * DIM + k0 + lcol, &Bs[brow * 32 + lcol]);
        GLDS(Wob + (size_t)(n0 + brow + 16) * DIM + k0 + lcol, &Bs[(brow + 16) * 32 + lcol]);
        __syncthreads();

        v8bf16 af[2], bf[3];
#pragma unroll
        for (int i = 0; i < 2; ++i)
            af[i] = *(const v8bf16*)&As[(wm * 32 + i * 16 + low4) * 32 + quad * 8];
#pragma unroll
        for (int j = 0; j < 3; ++j)
            bf[j] = *(const v8bf16*)&Bs[(wn * 48 + j * 16 + low4) * 32 + quad * 8];
#pragma unroll
        for (int i = 0; i < 2; ++i)
#pragma unroll
            for (int j = 0; j < 3; ++j)
                acc[i][j] = __builtin_amdgcn_mfma_f32_16x16x32_bf16(af[i], bf[j], acc[i][j], 0, 0, 0);
        __syncthreads();
    }

#pragma unroll
    for (int j = 0; j < 3; ++j) {
        const int e = n0 + wn * 48 + j * 16 + low4;
        const float b = bo[e];
#pragma unroll
        for (int i = 0; i < 2; ++i) {
#pragma unroll
            for (int r = 0; r < 4; ++r) {
                const int m = m0 + wm * 32 + i * 16 + quad * 4 + r;
                outp[(size_t)m * DIM + e] = acc[i][j][r] + b;
            }
        }
    }
}

// ---------------------------------------------------------------------------
// MFMA flash attention (R8-proven), SPLIT-K (z = key half), no-max softmax
// (exact: shift-invariant + bounded scores; Q pre-scaled by log2e/sqrt(48)).
// Block = 4 waves, 128 queries, 1024 keys. Register-prefetch double buffer
// for K/V staging. Qs/Ps share one LDS array. l via ones-B-fragment MFMA.
// Outputs UNNORMALIZED O (bf16) + l (fp32).
// ---------------------------------------------------------------------------
__global__ __launch_bounds__(256) void attention_kernel(
    const __bf16* __restrict__ Q, const __bf16* __restrict__ K,
    const __bf16* __restrict__ Vt_g, __bf16* __restrict__ Opart,
    float* __restrict__ lbuf)
{
    __shared__ __bf16 PQ[128][72];  // Qs during init, then Ps (XOR-swizzled)
    __shared__ __bf16 Ks[64][72];   // [key][dk padded 48->64]
    __shared__ __bf16 Vt[48][72];   // [d][key]

    const int bh   = blockIdx.y;
    const int q0   = blockIdx.x * 128;
    const int kh0  = blockIdx.z * 1024;   // key half start
    const int t    = threadIdx.x;
    const int w    = t >> 6;
    const int lane = t & 63;
    const int low4 = lane & 15;
    const int quad = lane >> 4;

    const __bf16* Qbh = Q    + (size_t)bh * SEQ * DKH;
    const __bf16* Kbh = K    + (size_t)bh * SEQ * DKH;
    const __bf16* Vbh = Vt_g + (size_t)bh * SEQ * DKH;  // [d][s]

    // ---- stage Q tile (128 x 48, pre-scaled); zero pad cols 48..63 ----
    {
        const int row = t >> 1;
        const int c0  = (t & 1) * 24;
        const __bf16* src = &Qbh[(size_t)(q0 + row) * DKH + c0];
#pragma unroll
        for (int jj = 0; jj < 6; ++jj)
            *(v4bf16*)&PQ[row][c0 + jj * 4] = *(const v4bf16*)&src[jj * 4];
        v4bf16 zz = {(__bf16)0.f, (__bf16)0.f, (__bf16)0.f, (__bf16)0.f};
        *(v4bf16*)&PQ[row][48 + (t & 1) * 8]     = zz;
        *(v4bf16*)&PQ[row][48 + (t & 1) * 8 + 4] = zz;
        *(v4bf16*)&Ks[t >> 2][48 + (t & 3) * 4]  = zz;   // Ks pad cols 48..63
    }
    __syncthreads();

    // Q A-fragments: wave w owns query rows w*32 .. w*32+31 (tiles i=0,1)
    v8bf16 aq[2][2];
#pragma unroll
    for (int i = 0; i < 2; ++i)
#pragma unroll
        for (int ks = 0; ks < 2; ++ks)
            aq[i][ks] = *(const v8bf16*)&PQ[w * 32 + i * 16 + low4][ks * 32 + quad * 8];

    // ones B-fragment for l row-sums
    v8bf16 ones;
#pragma unroll
    for (int jj = 0; jj < 8; ++jj) ones[jj] = (__bf16)1.0f;

    v4f32 lacc[2];
    v4f32 oacc[2][3];
#pragma unroll
    for (int i = 0; i < 2; ++i) {
        lacc[i] = (v4f32){0.f, 0.f, 0.f, 0.f};
#pragma unroll
        for (int dt = 0; dt < 3; ++dt)
            oacc[i][dt] = (v4f32){0.f, 0.f, 0.f, 0.f};
    }

    // staging coords
    const int krow = t >> 2;            // K: key row 0..63
    const int kc0  = (t & 3) * 12;      // K: dk chunk
    const int vrow = t >> 2;            // V^T: d row 0..47 (t < 192)
    const int vc0  = (t & 3) * 16;      // V^T: key chunk
    const int pswz = (low4 >> 2) * 8;   // Ps read swizzle

    // ---- prefetch tile 0 into registers ----
    v4bf16 kreg[3];
    v8bf16 vreg0, vreg1;
    {
        const __bf16* sk = &Kbh[(size_t)(kh0 + krow) * DKH + kc0];
        kreg[0] = *(const v4bf16*)&sk[0];
        kreg[1] = *(const v4bf16*)&sk[4];
        kreg[2] = *(const v4bf16*)&sk[8];
        if (t < 192) {
            const __bf16* sv = &Vbh[(size_t)vrow * SEQ + kh0 + vc0];
            vreg0 = *(const v8bf16*)&sv[0];
            vreg1 = *(const v8bf16*)&sv[8];
        }
    }

    for (int k0 = kh0; k0 < kh0 + 1024; k0 += 64) {
        __syncthreads();   // prior LDS reads done (and Q frag reads, iter 0)

        // ---- write prefetched tile to LDS ----
#pragma unroll
        for (int jj = 0; jj < 3; ++jj)
            *(v4bf16*)&Ks[krow][kc0 + jj * 4] = kreg[jj];
        if (t < 192) {
            *(v8bf16*)&Vt[vrow][vc0]     = vreg0;
            *(v8bf16*)&Vt[vrow][vc0 + 8] = vreg1;
        }

        // ---- issue prefetch for next tile (overlaps compute below) ----
        if (k0 + 64 < kh0 + 1024) {
            const __bf16* sk = &Kbh[(size_t)(k0 + 64 + krow) * DKH + kc0];
            kreg[0] = *(const v4bf16*)&sk[0];
            kreg[1] = *(const v4bf16*)&sk[4];
            kreg[2] = *(const v4bf16*)&sk[8];
            if (t < 192) {
                const __bf16* sv = &Vbh[(size_t)vrow * SEQ + (k0 + 64) + vc0];
                vreg0 = *(const v8bf16*)&sv[0];
                vreg1 = *(const v8bf16*)&sv[8];
            }
        }
        __syncthreads();

        // ---- K B-fragments (shared across both query tiles) ----
        v8bf16 bk0[4], bk1[4];
#pragma unroll
        for (int tn = 0; tn < 4; ++tn) {
            bk0[tn] = *(const v8bf16*)&Ks[tn * 16 + low4][quad * 8];
            bk1[tn] = *(const v8bf16*)&Ks[tn * 16 + low4][32 + quad * 8];
        }

        // ---- S = Q K^T, p = exp2(s), P -> LDS (wave-private rows) ----
#pragma unroll
        for (int i = 0; i < 2; ++i) {
            v4f32 sacc[4];
#pragma unroll
            for (int tn = 0; tn < 4; ++tn) {
                v4f32 c = {0.f, 0.f, 0.f, 0.f};
                c = __builtin_amdgcn_mfma_f32_16x16x32_bf16(aq[i][0], bk0[tn], c, 0, 0, 0);
                c = __builtin_amdgcn_mfma_f32_16x16x32_bf16(aq[i][1], bk1[tn], c, 0, 0, 0);
                sacc[tn] = c;
            }
#pragma unroll
            for (int tn = 0; tn < 4; ++tn) {
#pragma unroll
                for (int r = 0; r < 4; ++r) {
                    const float p = __builtin_amdgcn_exp2f(sacc[tn][r]);
                    PQ[w * 32 + i * 16 + quad * 4 + r][(tn * 16 + low4) ^ (quad * 8)] = (__bf16)p;
                }
            }
        }

        // ---- O += P @ V; l += P @ ones ----
        v8bf16 bv0[3], bv1[3];
#pragma unroll
        for (int dt = 0; dt < 3; ++dt) {
            bv0[dt] = *(const v8bf16*)&Vt[dt * 16 + low4][quad * 8];
            bv1[dt] = *(const v8bf16*)&Vt[dt * 16 + low4][32 + quad * 8];
        }
#pragma unroll
        for (int i = 0; i < 2; ++i) {
            v8bf16 ap0 = *(const v8bf16*)&PQ[w * 32 + i * 16 + low4][(quad * 8) ^ pswz];
            v8bf16 ap1 = *(const v8bf16*)&PQ[w * 32 + i * 16 + low4][(32 + quad * 8) ^ pswz];
#pragma unroll
            for (int dt = 0; dt < 3; ++dt) {
                oacc[i][dt] = __builtin_amdgcn_mfma_f32_16x16x32_bf16(ap0, bv0[dt], oacc[i][dt], 0, 0, 0);
                oacc[i][dt] = __builtin_amdgcn_mfma_f32_16x16x32_bf16(ap1, bv1[dt], oacc[i][dt], 0, 0, 0);
            }
            lacc[i] = __builtin_amdgcn_mfma_f32_16x16x32_bf16(ap0, ones, lacc[i], 0, 0, 0);
            lacc[i] = __builtin_amdgcn_mfma_f32_16x16x32_bf16(ap1, ones, lacc[i], 0, 0, 0);
        }
    }

    // ---- write unnormalized O partial (bf16) + l (fp32) ----
    const int kh = blockIdx.z;
#pragma unroll
    for (int i = 0; i < 2; ++i) {
#pragma unroll
        for (int r = 0; r < 4; ++r) {
            const int s  = q0 + w * 32 + i * 16 + quad * 4 + r;
            const int qg = bh * SEQ + s;
            __bf16* dst = Opart + (size_t)kh * PART + (size_t)qg * 48;
#pragma unroll
            for (int dt = 0; dt < 3; ++dt)
                dst[dt * 16 + low4] = (__bf16)oacc[i][dt][r];
            if (low4 == 0)
                lbuf[kh * QTOT + qg] = lacc[i][r];
        }
    }
}

// ---------------------------------------------------------------------------
extern "C" void kernel_launch(void* const* d_in, const int* in_sizes, int n_in,
                              void* d_out, int out_size, void* d_ws, size_t ws_size,
                              hipStream_t stream) {
    const float* x  = (const float*)d_in[0];
    const float* Wq = (const float*)d_in[1];
    const float* bq = (const float*)d_in[2];
    const float* Wk = (const float*)d_in[3];
    const float* bk = (const float*)d_in[4];
    const float* Wv = (const float*)d_in[5];
    const float* bv = (const float*)d_in[6];
    const float* Wo = (const float*)d_in[7];
    const float* bo = (const float*)d_in[8];
    float* out = (float*)d_out;

    char* ws = (char*)d_ws;
    const size_t XB  = (size_t)M_TOT * DIM * 2;    // 6291456
    const size_t WBP = (size_t)800 * DIM * 2;      // 1228800 (768 rows + 32 pad)
    __bf16* xb  = (__bf16*)(ws);
    __bf16* Wqb = (__bf16*)(ws + XB);
    __bf16* Wkb = (__bf16*)(ws + XB + WBP);
    __bf16* Wvb = (__bf16*)(ws + XB + 2 * WBP);
    __bf16* Wob = (__bf16*)(ws + XB + 3 * WBP);
    __bf16* Qb  = (__bf16*)(ws + XB + 4 * WBP);
    __bf16* Kb  = (__bf16*)(ws + 2 * XB + 4 * WBP);
    __bf16* Vb  = (__bf16*)(ws + 3 * XB + 4 * WBP);  // [B,H,dk,S]
    float*  invl = (float*)(ws + 4 * XB + 4 * WBP);  // reuses old CTX slot
    __bf16* Opart = (__bf16*)(ws + 5 * XB + 4 * WBP);              // 2*PART bf16
    float*  lbuf  = (float*)(ws + 5 * XB + 4 * WBP + (size_t)2 * PART * 2);

    // 0) fp32 -> bf16 conversion of x and weights
    convert_kernel<<<dim3((XN4 + 4 * WN4) / 256), 256, 0, stream>>>(
        x, Wq, Wk, Wv, Wo, xb, Wqb, Wkb, Wvb, Wob);

    // 1) QKV projections (MFMA, BK=64): grid (8, 32, 3) = 768 blocks
    qkv_mfma_kernel<<<dim3(8, 32, 3), 256, 0, stream>>>(
        xb, Wqb, bq, Wkb, bk, Wvb, bv, Qb, Kb, Vb);

    // 2) attention split-K: grid (16, 32, 2)
    attention_kernel<<<dim3(16, 32, 2), 256, 0, stream>>>(Qb, Kb, Vb, Opart, lbuf);

    // 2b) l sums: 65536 / 256 = 256 blocks
    lsum_kernel<<<dim3(256), 256, 0, stream>>>(lbuf, invl);

    // 3) output projection with fused merge: grid (8, 64) = 512 blocks
    out_mfma_kernel<<<dim3(8, 64), 256, 0, stream>>>(Opart, invl, Wob, bo, out);
}

// Round 11
// 177.928 us; speedup vs baseline: 1.1722x; 1.0175x over previous
//
#include <hip/hip_runtime.h>
#include <math.h>

#define DIM 768
#define HEADS 16
#define DKH 48          // head dim
#define SEQ 2048
#define BATCH 2
#define M_TOT (BATCH*SEQ)                  // 4096

typedef __bf16 v8bf16 __attribute__((ext_vector_type(8)));
typedef __bf16 v4bf16 __attribute__((ext_vector_type(4)));
typedef float  v4f32  __attribute__((ext_vector_type(4)));

#define GLDS(g, l) __builtin_amdgcn_global_load_lds( \
    (const __attribute__((address_space(1))) void*)(g), \
    (__attribute__((address_space(3))) void*)(l), 16, 0, 0)

// ---------------------------------------------------------------------------
// fp32 -> bf16 conversion of x and the 4 weight matrices.
// ---------------------------------------------------------------------------
#define XN4 786432      // 4096*768/4
#define WN4 147456      // 768*768/4
__global__ __launch_bounds__(256) void convert_kernel(
    const float* __restrict__ x,
    const float* __restrict__ Wq, const float* __restrict__ Wk,
    const float* __restrict__ Wv, const float* __restrict__ Wo,
    __bf16* __restrict__ xb,
    __bf16* __restrict__ Wqb, __bf16* __restrict__ Wkb,
    __bf16* __restrict__ Wvb, __bf16* __restrict__ Wob)
{
    int f = blockIdx.x * 256 + threadIdx.x;
    const float* src; __bf16* dst;
    if (f < XN4)                { src = x;  dst = xb; }
    else if (f < XN4 + WN4)     { src = Wq; dst = Wqb; f -= XN4; }
    else if (f < XN4 + 2*WN4)   { src = Wk; dst = Wkb; f -= XN4 + WN4; }
    else if (f < XN4 + 3*WN4)   { src = Wv; dst = Wvb; f -= XN4 + 2*WN4; }
    else                        { src = Wo; dst = Wob; f -= XN4 + 3*WN4; }
    float4 v = ((const float4*)src)[f];
    v4bf16 b;
    b[0] = (__bf16)v.x; b[1] = (__bf16)v.y;
    b[2] = (__bf16)v.z; b[3] = (__bf16)v.w;
    *(v4bf16*)&dst[(size_t)f * 4] = b;
}

// ---------------------------------------------------------------------------
// QKV MFMA GEMM (R8-proven): BK=32, 128x96 tile -> grid (8,32,3) = 768 blocks.
// z=0: Q (scaled by log2e/sqrt(48)) -> [B,H,S,dk]. z=1: K -> [B,H,S,dk].
// z=2: V -> TRANSPOSED [B,H,dk,S] via b64 stores.
// ---------------------------------------------------------------------------
__global__ __launch_bounds__(256) void qkv_mfma_kernel(
    const __bf16* __restrict__ xb,
    const __bf16* __restrict__ Wqb, const float* __restrict__ bq,
    const __bf16* __restrict__ Wkb, const float* __restrict__ bk,
    const __bf16* __restrict__ Wvb, const float* __restrict__ bv,
    __bf16* __restrict__ Qo, __bf16* __restrict__ Ko, __bf16* __restrict__ Vo)
{
    __shared__ __bf16 As[128 * 32];
    __shared__ __bf16 Bs[128 * 32];

    const int z = blockIdx.z;
    const __bf16* W   = (z == 0) ? Wqb : ((z == 1) ? Wkb : Wvb);
    const float* bias = (z == 0) ? bq  : ((z == 1) ? bk  : bv);
    __bf16* out       = (z == 0) ? Qo  : ((z == 1) ? Ko  : Vo);

    const int m0 = blockIdx.y * 128;
    const int n0 = blockIdx.x * 96;
    const int t  = threadIdx.x;
    const int w    = t >> 6;
    const int lane = t & 63;
    const int low4 = lane & 15;
    const int quad = lane >> 4;
    const int wm = w >> 1, wn = w & 1;

    const int lrow = w * 32 + (lane >> 2);   // LDS row this lane stages
    const int lcol = (lane & 3) * 8;         // k-element offset (16 B)

    v4f32 acc[4][3];
#pragma unroll
    for (int i = 0; i < 4; ++i)
#pragma unroll
        for (int j = 0; j < 3; ++j)
            acc[i][j] = (v4f32){0.f, 0.f, 0.f, 0.f};

    for (int k0 = 0; k0 < DIM; k0 += 32) {
        GLDS(xb + (size_t)(m0 + lrow)      * DIM + k0 + lcol, &As[lrow * 32 + lcol]);
        GLDS(xb + (size_t)(m0 + lrow + 16) * DIM + k0 + lcol, &As[(lrow + 16) * 32 + lcol]);
        GLDS(W  + (size_t)(n0 + lrow)      * DIM + k0 + lcol, &Bs[lrow * 32 + lcol]);
        GLDS(W  + (size_t)(n0 + lrow + 16) * DIM + k0 + lcol, &Bs[(lrow + 16) * 32 + lcol]);
        __syncthreads();

        v8bf16 af[4], bf[3];
#pragma unroll
        for (int i = 0; i < 4; ++i)
            af[i] = *(const v8bf16*)&As[(wm * 64 + i * 16 + low4) * 32 + quad * 8];
#pragma unroll
        for (int j = 0; j < 3; ++j)
            bf[j] = *(const v8bf16*)&Bs[(wn * 48 + j * 16 + low4) * 32 + quad * 8];
#pragma unroll
        for (int i = 0; i < 4; ++i)
#pragma unroll
            for (int j = 0; j < 3; ++j)
                acc[i][j] = __builtin_amdgcn_mfma_f32_16x16x32_bf16(af[i], bf[j], acc[i][j], 0, 0, 0);
        __syncthreads();
    }

    // scale = log2(e)/sqrt(48), folded into Q so attention can use exp2
    const float scale = 0.2082351055f;
#pragma unroll
    for (int j = 0; j < 3; ++j) {
        const int e = n0 + wn * 48 + j * 16 + low4;
        const float b = bias[e];
        const int h = e / DKH;
        const int d = e - h * DKH;
        if (z == 2) {
            // V^T: 4 consecutive s per lane -> one b64 store
#pragma unroll
            for (int i = 0; i < 4; ++i) {
                const int m_base = m0 + wm * 64 + i * 16 + quad * 4;
                const int bb = m_base >> 11;
                const int s  = m_base & (SEQ - 1);
                v4bf16 pk;
#pragma unroll
                for (int r = 0; r < 4; ++r) pk[r] = (__bf16)(acc[i][j][r] + b);
                *(v4bf16*)&out[((size_t)(bb * HEADS + h) * DKH + d) * SEQ + s] = pk;
            }
        } else {
#pragma unroll
            for (int i = 0; i < 4; ++i) {
#pragma unroll
                for (int r = 0; r < 4; ++r) {
                    const int m  = m0 + wm * 64 + i * 16 + quad * 4 + r;
                    const int bb = m >> 11;
                    const int s  = m & (SEQ - 1);
                    float v = acc[i][j][r] + b;
                    if (z == 0) v *= scale;
                    out[((size_t)(bb * HEADS + h) * SEQ + s) * DKH + d] = (__bf16)v;
                }
            }
        }
    }
}

// ---------------------------------------------------------------------------
// Output projection (R8-proven): out[m][e] = ctx[m][:].Wo[e][:] + bo[e].
// 64x96 tile -> grid (8,64) = 512 blocks = 2.00 blocks/CU.
// ---------------------------------------------------------------------------
__global__ __launch_bounds__(256) void out_mfma_kernel(
    const __bf16* __restrict__ ctx, const __bf16* __restrict__ Wob,
    const float* __restrict__ bo, float* __restrict__ outp)
{
    __shared__ __bf16 As[64 * 32];
    __shared__ __bf16 Bs[128 * 32];

    const int m0 = blockIdx.y * 64;
    const int n0 = blockIdx.x * 96;
    const int t  = threadIdx.x;
    const int w    = t >> 6;
    const int lane = t & 63;
    const int low4 = lane & 15;
    const int quad = lane >> 4;
    const int wm = w >> 1, wn = w & 1;

    const int arow = w * 16 + (lane >> 2);   // As staging row (0..63)
    const int brow = w * 32 + (lane >> 2);   // Bs staging rows (0..127)
    const int lcol = (lane & 3) * 8;

    v4f32 acc[2][3];
#pragma unroll
    for (int i = 0; i < 2; ++i)
#pragma unroll
        for (int j = 0; j < 3; ++j)
            acc[i][j] = (v4f32){0.f, 0.f, 0.f, 0.f};

    for (int k0 = 0; k0 < DIM; k0 += 32) {
        GLDS(ctx + (size_t)(m0 + arow)      * DIM + k0 + lcol, &As[arow * 32 + lcol]);
        GLDS(Wob + (size_t)(n0 + brow)      * DIM + k0 + lcol, &Bs[brow * 32 + lcol]);
        GLDS(Wob + (size_t)(n0 + brow + 16) * DIM + k0 + lcol, &Bs[(brow + 16) * 32 + lcol]);
        __syncthreads();

        v8bf16 af[2], bf[3];
#pragma unroll
        for (int i = 0; i < 2; ++i)
            af[i] = *(const v8bf16*)&As[(wm * 32 + i * 16 + low4) * 32 + quad * 8];
#pragma unroll
        for (int j = 0; j < 3; ++j)
            bf[j] = *(const v8bf16*)&Bs[(wn * 48 + j * 16 + low4) * 32 + quad * 8];
#pragma unroll
        for (int i = 0; i < 2; ++i)
#pragma unroll
            for (int j = 0; j < 3; ++j)
                acc[i][j] = __builtin_amdgcn_mfma_f32_16x16x32_bf16(af[i], bf[j], acc[i][j], 0, 0, 0);
        __syncthreads();
    }

#pragma unroll
    for (int j = 0; j < 3; ++j) {
        const int e = n0 + wn * 48 + j * 16 + low4;
        const float b = bo[e];
#pragma unroll
        for (int i = 0; i < 2; ++i) {
#pragma unroll
            for (int r = 0; r < 4; ++r) {
                const int m = m0 + wm * 32 + i * 16 + quad * 4 + r;
                outp[(size_t)m * DIM + e] = acc[i][j][r] + b;
            }
        }
    }
}

// ---------------------------------------------------------------------------
// WAVE-SPLIT-K barrier-free MFMA flash attention.
// Block = 64 queries x full 2048 keys; wave w owns key strip w*32 + 128*t
// (disjoint across waves -> each K/V element loaded by exactly ONE wave,
// straight from global into B-frags; Q A-frags register-resident).
// No-max softmax (exact: shift-invariant, bounded scores; Q pre-scaled by
// log2e/sqrt(48) -> exp2). Unnormalized O/l accumulate per wave; k-loop has
// ZERO barriers. Epilogue: LDS reduction across waves (5 barriers), then
// normalized bf16 ctx written directly ([B,S,768]).
// LDS: per-wave P (64x32, stride 40, XOR-swizzled) + f32 reduction buffers.
// ---------------------------------------------------------------------------
__global__ __launch_bounds__(256) void attention_kernel(
    const __bf16* __restrict__ Q, const __bf16* __restrict__ K,
    const __bf16* __restrict__ Vt_g, __bf16* __restrict__ ctx)
{
    __shared__ __bf16 Ps[4][64 * 40];   // 20480 B, wave-private P
    __shared__ float  rbuf[64][52];     // 13312 B, O reduction
    __shared__ float  lrbuf[64];        // l reduction

    const int bh   = blockIdx.y;
    const int q0   = blockIdx.x * 64;
    const int t    = threadIdx.x;
    const int w    = t >> 6;
    const int lane = t & 63;
    const int low4 = lane & 15;
    const int quad = lane >> 4;

    const __bf16* Qbh = Q    + (size_t)bh * SEQ * DKH;
    const __bf16* Kbh = K    + (size_t)bh * SEQ * DKH;
    const __bf16* Vbh = Vt_g + (size_t)bh * SEQ * DKH;  // [d][s]

    v8bf16 zz8;
#pragma unroll
    for (int jj = 0; jj < 8; ++jj) zz8[jj] = (__bf16)0.f;
    v8bf16 ones;
#pragma unroll
    for (int jj = 0; jj < 8; ++jj) ones[jj] = (__bf16)1.0f;

    // ---- Q A-fragments (register-resident, loaded once) ----
    v8bf16 aq[4][2];
#pragma unroll
    for (int i = 0; i < 4; ++i) {
        const __bf16* qrow = &Qbh[(size_t)(q0 + i * 16 + low4) * DKH];
        aq[i][0] = *(const v8bf16*)&qrow[quad * 8];
        aq[i][1] = zz8;
        if (quad < 2)
            aq[i][1] = *(const v8bf16*)&qrow[32 + quad * 8];
    }

    v4f32 oacc[4][3];
    v4f32 lacc[4];
#pragma unroll
    for (int i = 0; i < 4; ++i) {
        lacc[i] = (v4f32){0.f, 0.f, 0.f, 0.f};
#pragma unroll
        for (int dt = 0; dt < 3; ++dt)
            oacc[i][dt] = (v4f32){0.f, 0.f, 0.f, 0.f};
    }

    __bf16* myP = &Ps[w][0];
    const int pswz = (low4 >> 2) * 8;

    // ---- barrier-free k-loop: wave strip = w*32 + 128*t ----
    for (int k0 = w * 32; k0 < SEQ; k0 += 128) {
        // K B-frags (2 key sub-tiles x 2 k-halves; dk 48..63 = zero frag)
        v8bf16 bk[2][2];
#pragma unroll
        for (int tn = 0; tn < 2; ++tn) {
            const __bf16* krow = &Kbh[(size_t)(k0 + tn * 16 + low4) * DKH];
            bk[tn][0] = *(const v8bf16*)&krow[quad * 8];
            bk[tn][1] = zz8;
            if (quad < 2)
                bk[tn][1] = *(const v8bf16*)&krow[32 + quad * 8];
        }
        // V^T B-frags (3 d-tiles, k = 32 keys)
        v8bf16 bv[3];
#pragma unroll
        for (int dt = 0; dt < 3; ++dt)
            bv[dt] = *(const v8bf16*)&Vbh[(size_t)(dt * 16 + low4) * SEQ + k0 + quad * 8];

#pragma unroll
        for (int i = 0; i < 4; ++i) {
            // S = Q K^T for q-tile i vs 32-key strip
            v4f32 s[2];
#pragma unroll
            for (int tn = 0; tn < 2; ++tn) {
                v4f32 c = {0.f, 0.f, 0.f, 0.f};
                c = __builtin_amdgcn_mfma_f32_16x16x32_bf16(aq[i][0], bk[tn][0], c, 0, 0, 0);
                c = __builtin_amdgcn_mfma_f32_16x16x32_bf16(aq[i][1], bk[tn][1], c, 0, 0, 0);
                s[tn] = c;
            }
            // exp2, P -> wave-private LDS (swizzled)
#pragma unroll
            for (int tn = 0; tn < 2; ++tn)
#pragma unroll
                for (int r = 0; r < 4; ++r) {
                    const float p = __builtin_amdgcn_exp2f(s[tn][r]);
                    myP[(i * 16 + quad * 4 + r) * 40 + ((tn * 16 + low4) ^ (quad * 8))] = (__bf16)p;
                }
            // P A-frag, O += P V, l += P 1
            v8bf16 ap = *(const v8bf16*)&myP[(i * 16 + low4) * 40 + ((quad * 8) ^ pswz)];
#pragma unroll
            for (int dt = 0; dt < 3; ++dt)
                oacc[i][dt] = __builtin_amdgcn_mfma_f32_16x16x32_bf16(ap, bv[dt], oacc[i][dt], 0, 0, 0);
            lacc[i] = __builtin_amdgcn_mfma_f32_16x16x32_bf16(ap, ones, lacc[i], 0, 0, 0);
        }
    }

    // ---- epilogue: cross-wave O/l reduction in LDS ----
    __syncthreads();
#pragma unroll
    for (int ww = 0; ww < 4; ++ww) {
        if (w == ww) {
#pragma unroll
            for (int i = 0; i < 4; ++i) {
#pragma unroll
                for (int dt = 0; dt < 3; ++dt)
#pragma unroll
                    for (int r = 0; r < 4; ++r) {
                        const int q = i * 16 + quad * 4 + r;
                        const int d = dt * 16 + low4;
                        if (ww == 0) rbuf[q][d]  = oacc[i][dt][r];
                        else         rbuf[q][d] += oacc[i][dt][r];
                    }
                if (low4 == 0) {
#pragma unroll
                    for (int r = 0; r < 4; ++r) {
                        const int q = i * 16 + quad * 4 + r;
                        if (ww == 0) lrbuf[q]  = lacc[i][r];
                        else         lrbuf[q] += lacc[i][r];
                    }
                }
            }
        }
        __syncthreads();
    }

    // ---- normalize + write ctx [B,S,768] bf16 ----
    {
        const int h  = bh & (HEADS - 1);
        const int bb = bh >> 4;
        const int q  = t >> 2;
        const int d0 = (t & 3) * 12;
        const float inv = 1.0f / lrbuf[q];
        __bf16* dst = ctx + ((size_t)(bb * SEQ + q0 + q) * DIM) + h * DKH + d0;
#pragma unroll
        for (int jj = 0; jj < 3; ++jj) {
            v4bf16 pk;
#pragma unroll
            for (int e = 0; e < 4; ++e)
                pk[e] = (__bf16)(rbuf[q][d0 + jj * 4 + e] * inv);
            *(v4bf16*)&dst[jj * 4] = pk;
        }
    }
}

// ---------------------------------------------------------------------------
extern "C" void kernel_launch(void* const* d_in, const int* in_sizes, int n_in,
                              void* d_out, int out_size, void* d_ws, size_t ws_size,
                              hipStream_t stream) {
    const float* x  = (const float*)d_in[0];
    const float* Wq = (const float*)d_in[1];
    const float* bq = (const float*)d_in[2];
    const float* Wk = (const float*)d_in[3];
    const float* bk = (const float*)d_in[4];
    const float* Wv = (const float*)d_in[5];
    const float* bv = (const float*)d_in[6];
    const float* Wo = (const float*)d_in[7];
    const float* bo = (const float*)d_in[8];
    float* out = (float*)d_out;

    char* ws = (char*)d_ws;
    const size_t XB  = (size_t)M_TOT * DIM * 2;    // 6291456
    const size_t WBP = (size_t)800 * DIM * 2;      // 1228800 (768 rows + 32 pad)
    __bf16* xb  = (__bf16*)(ws);
    __bf16* Wqb = (__bf16*)(ws + XB);
    __bf16* Wkb = (__bf16*)(ws + XB + WBP);
    __bf16* Wvb = (__bf16*)(ws + XB + 2 * WBP);
    __bf16* Wob = (__bf16*)(ws + XB + 3 * WBP);
    __bf16* Qb  = (__bf16*)(ws + XB + 4 * WBP);
    __bf16* Kb  = (__bf16*)(ws + 2 * XB + 4 * WBP);
    __bf16* Vb  = (__bf16*)(ws + 3 * XB + 4 * WBP);  // [B,H,dk,S]
    __bf16* CTX = (__bf16*)(ws + 4 * XB + 4 * WBP);

    // 0) fp32 -> bf16 conversion of x and weights
    convert_kernel<<<dim3((XN4 + 4 * WN4) / 256), 256, 0, stream>>>(
        x, Wq, Wk, Wv, Wo, xb, Wqb, Wkb, Wvb, Wob);

    // 1) QKV projections (MFMA, BK=32): grid (8, 32, 3) = 768 blocks
    qkv_mfma_kernel<<<dim3(8, 32, 3), 256, 0, stream>>>(
        xb, Wqb, bq, Wkb, bk, Wvb, bv, Qb, Kb, Vb);

    // 2) attention (wave-split-K, barrier-free): grid (2048/64=32, 32)
    attention_kernel<<<dim3(32, 32), 256, 0, stream>>>(Qb, Kb, Vb, CTX);

    // 3) output projection: grid (8, 64) = 512 blocks
    out_mfma_kernel<<<dim3(8, 64), 256, 0, stream>>>(CTX, Wob, bo, out);
}